// Round 4
// baseline (275.927 us; speedup 1.0000x reference)
//
#include <hip/hip_runtime.h>
#include <hip/hip_bf16.h>
#include <cmath>

// Problem constants
#define B_SZ 8
#define L_SZ 2048
#define D_SZ 1024
#define CH 341
#define CP 384               // padded channel dim (2 x 192)
#define LCONV 2046           // L - KERNEL + 1
#define NSEG 512
#define KDIM 3072            // 3 * 1024 folded conv K
#define BK 64

#define POOLED_N (B_SZ * NSEG * D_SZ)

typedef _Float16 f16x8 __attribute__((ext_vector_type(8)));
typedef float f32x4 __attribute__((ext_vector_type(4)));

__device__ __forceinline__ void gl_lds16(const void* g, void* l) {
    __builtin_amdgcn_global_load_lds(
        (const __attribute__((address_space(1))) unsigned int*)g,
        (__attribute__((address_space(3))) unsigned int*)l, 16, 0, 0);
}

// ---------------------------------------------------------------------------
// Convert hidden fp32 -> fp16 (fixup kernel guarantees sign correctness of
// thresholded logits, so a single fp16 GEMM pass suffices)
// ---------------------------------------------------------------------------
__global__ __launch_bounds__(256) void convert_hidden_kernel(
        const float* __restrict__ hidden, _Float16* __restrict__ hid16) {
    size_t idx = (size_t)blockIdx.x * 256 + threadIdx.x;   // 8 elems / thread
    float4 v0 = ((const float4*)hidden)[idx * 2];
    float4 v1 = ((const float4*)hidden)[idx * 2 + 1];
    f16x8 o;
    o[0] = (_Float16)v0.x; o[1] = (_Float16)v0.y;
    o[2] = (_Float16)v0.z; o[3] = (_Float16)v0.w;
    o[4] = (_Float16)v1.x; o[5] = (_Float16)v1.y;
    o[6] = (_Float16)v1.z; o[7] = (_Float16)v1.w;
    ((f16x8*)hid16)[idx] = o;
}

// ---------------------------------------------------------------------------
// Convert w1 (Ch,D,K) -> bpack[c][k'=kk*1024+d] fp16, c padded to 384 with
// zeros. Also init logits to b2 and zero the two scalar outputs.
// ---------------------------------------------------------------------------
__global__ __launch_bounds__(256) void convert_w1_kernel(
        const float* __restrict__ w1, const float* __restrict__ b2,
        _Float16* __restrict__ bpack, float* __restrict__ logits,
        float* __restrict__ out_scalars) {
    int idx = blockIdx.x * 256 + threadIdx.x;   // < 384*3072
    int c = idx / KDIM;
    int kp = idx - c * KDIM;
    int kk = kp >> 10, d = kp & 1023;
    float v = (c < CH) ? w1[((size_t)c * 1024 + d) * 3 + kk] : 0.0f;
    bpack[idx] = (_Float16)v;
    if (idx < B_SZ * LCONV) logits[idx] = b2[0];
    if (idx == 0) { out_scalars[0] = 0.0f; out_scalars[1] = 0.0f; }
}

// ---------------------------------------------------------------------------
// fp16 MFMA conv GEMM, double-buffered LDS prefetch.
// Per batch: M=2046(l pad 2048) x N=384(c) x K=3072.
// A[l][k'] = hid16_flat[l*1024+k'] (folded conv: contiguous K walk).
// Block tile 64 l x 192 c, BK=64, 4 waves, wave-tile 64x48 (4x3 16x16x32).
// Grid (2,32,8) = 512 blocks = 2 blocks/CU. LDS 2 x (8KB A + 24KB B) = 64KB.
// Prefetch issued after barrier, before compute -> next barrier's vmcnt
// drain overlaps a full compute phase.
// Fused epilogue: relu(h+b1)*w2 reduced over c, atomicAdd into logits.
// ---------------------------------------------------------------------------
__global__ __launch_bounds__(256, 2) void conv_mfma_kernel(
        const _Float16* __restrict__ hid16, const _Float16* __restrict__ bpack,
        const float* __restrict__ b1, const float* __restrict__ w2,
        float* __restrict__ logits) {
    const int nt = blockIdx.x;           // 0..1
    const int mt = blockIdx.y;           // 0..31
    const int b  = blockIdx.z;
    const int l0 = mt * 64;
    const int n0 = nt * 192;
    const int tid = threadIdx.x;
    const int wave = tid >> 6, lane = tid & 63;
    const int quad = lane >> 4, l16 = lane & 15;

    __shared__ __align__(16) char lds[65536];   // 2 x (A 8K + B 24K)

    const _Float16* hb = hid16 + (size_t)b * L_SZ * D_SZ;

    // A staging: 512 entries/buf, 2 per thread.
    // entry f = kc*256 + i*64 + lane -> l = l0 + i*16 + (f&15),
    //                                   k = kc*32 + ((f>>4)&3)*8
    const _Float16* pa[2];
    #pragma unroll
    for (int p = 0; p < 2; ++p) {
        int f = p * 256 + tid;
        int kc = f >> 8, i = (f >> 6) & 3;
        int l = l0 + i * 16 + (f & 15);
        if (l > LCONV - 1) l = LCONV - 1;
        pa[p] = hb + (size_t)l * 1024 + kc * 32 + ((f >> 4) & 3) * 8;
    }
    // B staging: 1536 entries/buf, 6 per thread.
    // entry f = kc*768 + jn*64 + lane -> n = n0 + jn*16 + (f&15), k as above
    const _Float16* pb[6];
    #pragma unroll
    for (int p = 0; p < 6; ++p) {
        int f = p * 256 + tid;
        int kc = (f >= 768) ? 1 : 0;
        int jn = (f - kc * 768) >> 6;
        pb[p] = bpack + (size_t)(n0 + jn * 16 + (f & 15)) * KDIM
              + kc * 32 + ((f >> 4) & 3) * 8;
    }

    f32x4 acc[4][3] = {};

    // prologue: stage step 0 into buffer 0
    {
        char* dA = lds, *dB = lds + 8192;
        #pragma unroll
        for (int p = 0; p < 2; ++p) gl_lds16(pa[p], dA + (p * 256 + wave * 64) * 16);
        #pragma unroll
        for (int p = 0; p < 6; ++p) gl_lds16(pb[p], dB + (p * 256 + wave * 64) * 16);
        #pragma unroll
        for (int p = 0; p < 2; ++p) pa[p] += BK;
        #pragma unroll
        for (int p = 0; p < 6; ++p) pb[p] += BK;
    }

    for (int s = 0; s < KDIM / BK; ++s) {
        __syncthreads();                    // buf[s&1] ready (prev prefetch drained)
        if (s + 1 < KDIM / BK) {            // prefetch next into other buffer
            char* dA = lds + ((s + 1) & 1) * 32768;
            char* dB = dA + 8192;
            #pragma unroll
            for (int p = 0; p < 2; ++p) gl_lds16(pa[p], dA + (p * 256 + wave * 64) * 16);
            #pragma unroll
            for (int p = 0; p < 6; ++p) gl_lds16(pb[p], dB + (p * 256 + wave * 64) * 16);
            #pragma unroll
            for (int p = 0; p < 2; ++p) pa[p] += BK;
            #pragma unroll
            for (int p = 0; p < 6; ++p) pb[p] += BK;
        }
        const char* bp = lds + (s & 1) * 32768;
        #pragma unroll
        for (int kc = 0; kc < 2; ++kc) {
            f16x8 a[4], bb[3];
            #pragma unroll
            for (int ii = 0; ii < 4; ++ii)
                a[ii] = *(const f16x8*)(bp + (kc * 256 + ii * 64 + lane) * 16);
            #pragma unroll
            for (int jj = 0; jj < 3; ++jj)
                bb[jj] = *(const f16x8*)(bp + 8192 + (kc * 768 + (wave * 3 + jj) * 64 + lane) * 16);
            #pragma unroll
            for (int ii = 0; ii < 4; ++ii)
                #pragma unroll
                for (int jj = 0; jj < 3; ++jj)
                    acc[ii][jj] = __builtin_amdgcn_mfma_f32_16x16x32_f16(
                        a[ii], bb[jj], acc[ii][jj], 0, 0, 0);
        }
    }
    __syncthreads();

    // --- epilogue: relu(acc + b1)*w2, reduce over c, atomic into logits ---
    float cb1[3], cw2[3];
    #pragma unroll
    for (int jj = 0; jj < 3; ++jj) {
        int ch = n0 + wave * 48 + jj * 16 + l16;
        bool v = ch < CH;
        cb1[jj] = v ? b1[ch] : 0.0f;
        cw2[jj] = v ? w2[ch] : 0.0f;
    }
    float* red = (float*)lds;   // [64][4]
    #pragma unroll
    for (int ii = 0; ii < 4; ++ii)
        #pragma unroll
        for (int r = 0; r < 4; ++r) {
            float P = 0.0f;
            #pragma unroll
            for (int jj = 0; jj < 3; ++jj) {
                float h = acc[ii][jj][r] + cb1[jj];
                if (h > 0.0f) P += h * cw2[jj];
            }
            P += __shfl_xor(P, 1);
            P += __shfl_xor(P, 2);
            P += __shfl_xor(P, 4);
            P += __shfl_xor(P, 8);
            if (l16 == 0)
                red[(ii * 16 + quad * 4 + r) * 4 + wave] = P;
        }
    __syncthreads();
    if (tid < 64) {
        int l = l0 + tid;
        if (l < LCONV)
            atomicAdd(&logits[b * LCONV + l],
                      red[tid * 4] + red[tid * 4 + 1] + red[tid * 4 + 2] + red[tid * 4 + 3]);
    }
}

// ---------------------------------------------------------------------------
// Exact fp32 fixup: fp16-GEMM logit error sigma ~= 0.027, so any
// |logit| < 0.25 (~9 sigma) is recomputed exactly from hidden/w1 in fp32.
// Expected flagged: ~10 positions total -> microseconds.
// ---------------------------------------------------------------------------
__global__ __launch_bounds__(256) void fixup_kernel(
        const float* __restrict__ hidden, const float* __restrict__ w1,
        const float* __restrict__ b1, const float* __restrict__ w2,
        const float* __restrict__ b2, float* __restrict__ logits) {
    const int b = blockIdx.y, l0 = blockIdx.x * 64, tid = threadIdx.x;
    __shared__ float hrow[3 * 1024];
    __shared__ float sred[256];
    __shared__ int flags[64];
    __shared__ int nflag;
    if (tid == 0) nflag = 0;
    __syncthreads();
    if (tid < 64) {
        int l = l0 + tid;
        if (l < LCONV) {
            float v = logits[b * LCONV + l];
            if (fabsf(v) < 0.25f) { int k = atomicAdd(&nflag, 1); flags[k] = l; }
        }
    }
    __syncthreads();
    const int nf = nflag;
    for (int fi = 0; fi < nf; ++fi) {
        const int l = flags[fi];
        for (int t = tid; t < 3072; t += 256)
            hrow[t] = hidden[((size_t)b * L_SZ + l) * 1024 + t];
        __syncthreads();
        float tot = 0.0f;
        for (int c = tid; c < CH; c += 256) {
            const float* wr = w1 + (size_t)c * 3072;
            float dot = 0.0f;
            for (int d = 0; d < 1024; ++d)
                dot += hrow[d] * wr[d * 3] + hrow[1024 + d] * wr[d * 3 + 1]
                     + hrow[2048 + d] * wr[d * 3 + 2];
            float h = dot + b1[c];
            if (h > 0.0f) tot += h * w2[c];
        }
        sred[tid] = tot; __syncthreads();
        for (int off = 128; off > 0; off >>= 1) {
            if (tid < off) sred[tid] += sred[tid + off];
            __syncthreads();
        }
        if (tid == 0) logits[b * LCONV + l] = sred[0] + b2[0];
        __syncthreads();
    }
}

// ---------------------------------------------------------------------------
// Boundary scan: hard bits, segment starts, per-token segment ids,
// short_mask, scalar outputs.
// ---------------------------------------------------------------------------
__global__ void boundary_scan_kernel(const float* __restrict__ logits,
                                     const float* __restrict__ amask,
                                     int* __restrict__ segstart,
                                     int* __restrict__ segid,
                                     float* __restrict__ out_nb,
                                     float* __restrict__ out_tp,
                                     float* __restrict__ short_mask) {
    const int b = blockIdx.x, tid = threadIdx.x;
    __shared__ int sdata[256];
    __shared__ int s_len, s_total;

    int cnt = 0;
    #pragma unroll
    for (int j = 0; j < 8; ++j) {
        int l = tid * 8 + j;
        cnt += (amask[b * L_SZ + l] > 0.5f) ? 1 : 0;
    }
    sdata[tid] = cnt; __syncthreads();
    for (int off = 128; off > 0; off >>= 1) {
        if (tid < off) sdata[tid] += sdata[tid + off];
        __syncthreads();
    }
    if (tid == 0) s_len = sdata[0];
    __syncthreads();
    const int len = s_len;

    int bits[8]; int tsum = 0;
    #pragma unroll
    for (int j = 0; j < 8; ++j) {
        int l = tid * 8 + j;
        int h = 0;
        if (l >= 2 && l < len) h = (logits[b * LCONV + (l - 2)] > 0.0f) ? 1 : 0;
        if (len < L_SZ && l == len - 1) h = 1;
        bits[j] = h; tsum += h;
    }
    __syncthreads();
    sdata[tid] = tsum; __syncthreads();
    for (int off = 1; off < 256; off <<= 1) {
        int v = (tid >= off) ? sdata[tid - off] : 0;
        __syncthreads();
        sdata[tid] += v;
        __syncthreads();
    }
    const int texcl = sdata[tid] - tsum;
    if (tid == 255) s_total = sdata[255];
    __syncthreads();
    const int total = s_total;

    for (int s = tid; s <= NSEG; s += 256)
        segstart[b * (NSEG + 1) + s] = (s == 0) ? 0 : len;
    __syncthreads();
    int run = texcl;
    #pragma unroll
    for (int j = 0; j < 8; ++j) {
        int l = tid * 8 + j;
        int sv = -1;
        if (l < len && run < NSEG) sv = run;
        segid[b * L_SZ + l] = sv;
        if (bits[j]) {
            if (run + 1 <= NSEG) segstart[b * (NSEG + 1) + run + 1] = l + 1;
            run++;
        }
    }

    if (tid == 0) {
        atomicAdd(out_nb, (float)total);
        atomicAdd(out_tp, (float)len);
    }
    for (int s = tid; s < NSEG; s += 256)
        short_mask[b * NSEG + s] = (s < total) ? 1.0f : 0.0f;
}

// ---------------------------------------------------------------------------
// Pool accumulate: 16-token chunks, thread = 4 d over the chunk, atomic flush
// per segment run. Grid (128,8) = 1024 blocks x 256 threads.
// ---------------------------------------------------------------------------
__global__ __launch_bounds__(256) void pool_accum_kernel(
        const float* __restrict__ hidden, const int* __restrict__ segid,
        float* __restrict__ pooled) {
    const int chunk = blockIdx.x, b = blockIdx.y;
    const int tid = threadIdx.x;
    const int d0 = tid * 4;
    const int lbase = chunk * 16;
    const float* hb = hidden + (size_t)b * L_SZ * D_SZ + d0;
    const int* sg = segid + b * L_SZ + lbase;
    float4 acc = make_float4(0.f, 0.f, 0.f, 0.f);
    int cur = -1;
    #pragma unroll
    for (int t = 0; t < 16; ++t) {
        int sid = sg[t];
        if (sid != cur) {
            if (cur >= 0) {
                float* dst = pooled + ((size_t)(b * NSEG + cur)) * D_SZ + d0;
                atomicAdd(dst + 0, acc.x); atomicAdd(dst + 1, acc.y);
                atomicAdd(dst + 2, acc.z); atomicAdd(dst + 3, acc.w);
            }
            acc = make_float4(0.f, 0.f, 0.f, 0.f);
            cur = sid;
        }
        if (sid >= 0) {
            float4 v = *(const float4*)(hb + (size_t)(lbase + t) * D_SZ);
            acc.x += v.x; acc.y += v.y; acc.z += v.z; acc.w += v.w;
        }
    }
    if (cur >= 0) {
        float* dst = pooled + ((size_t)(b * NSEG + cur)) * D_SZ + d0;
        atomicAdd(dst + 0, acc.x); atomicAdd(dst + 1, acc.y);
        atomicAdd(dst + 2, acc.z); atomicAdd(dst + 3, acc.w);
    }
}

// ---------------------------------------------------------------------------
// Pool finalize: divide by count, add sinusoidal PE.
// ---------------------------------------------------------------------------
__global__ __launch_bounds__(256) void pool_final_kernel(
        float* __restrict__ pooled, const int* __restrict__ segstart) {
    const int s = blockIdx.x, b = blockIdx.y, tid = threadIdx.x;
    const int l0 = segstart[b * (NSEG + 1) + s];
    const int l1 = segstart[b * (NSEG + 1) + s + 1];
    const float inv = 1.0f / ((float)(l1 - l0) + 1e-9f);
    const int d0 = tid * 4;
    size_t o = ((size_t)(b * NSEG + s)) * D_SZ + d0;
    float4 v = *(float4*)(pooled + o);
    const float ce = -9.210340371976184f / 512.0f;
    const int i = d0 >> 1;
    const float a0 = (float)s * expf(ce * (float)i);
    const float a1 = (float)s * expf(ce * (float)(i + 1));
    float4 out;
    out.x = v.x * inv + sinf(a0);
    out.y = v.y * inv + cosf(a0);
    out.z = v.z * inv + sinf(a1);
    out.w = v.w * inv + cosf(a1);
    *(float4*)(pooled + o) = out;
}

// ---------------------------------------------------------------------------
extern "C" void kernel_launch(void* const* d_in, const int* in_sizes, int n_in,
                              void* d_out, int out_size, void* d_ws, size_t ws_size,
                              hipStream_t stream) {
    const float* hidden = (const float*)d_in[0];
    const float* amask  = (const float*)d_in[1];
    const float* w1     = (const float*)d_in[2];
    const float* b1     = (const float*)d_in[3];
    const float* w2     = (const float*)d_in[4];
    const float* b2     = (const float*)d_in[5];

    float* out    = (float*)d_out;
    float* pooled = out;
    float* nb     = out + POOLED_N;
    float* tp     = nb + 1;
    float* smask  = out + POOLED_N + 2;

    // zero pooled (atomics accumulate into it); scalars zeroed by convert_w1
    hipMemsetAsync(d_out, 0, (size_t)POOLED_N * sizeof(float), stream);

    const size_t HID_E = (size_t)B_SZ * L_SZ * D_SZ;           // 16,777,216
    const size_t OFF_HID16    = 0;
    const size_t OFF_BPACK    = OFF_HID16 + HID_E * 2;                 // 32 MB
    const size_t OFF_LOGITS   = OFF_BPACK + (size_t)CP * KDIM * 2;     // +2.25 MB
    const size_t OFF_SEGSTART = OFF_LOGITS + (size_t)B_SZ * LCONV * 4;
    const size_t OFF_SEGID    = OFF_SEGSTART + (size_t)B_SZ * (NSEG + 1) * 4;

    _Float16* hid16  = (_Float16*)((char*)d_ws + OFF_HID16);
    _Float16* bpack  = (_Float16*)((char*)d_ws + OFF_BPACK);
    float*    logits = (float*)((char*)d_ws + OFF_LOGITS);
    int*      segst  = (int*)((char*)d_ws + OFF_SEGSTART);
    int*      segid  = (int*)((char*)d_ws + OFF_SEGID);

    convert_hidden_kernel<<<(int)(HID_E / 8 / 256), 256, 0, stream>>>(hidden, hid16);
    convert_w1_kernel<<<(CP * KDIM) / 256, 256, 0, stream>>>(w1, b2, bpack, logits, nb);
    conv_mfma_kernel<<<dim3(2, 32, B_SZ), 256, 0, stream>>>(hid16, bpack, b1, w2, logits);
    fixup_kernel<<<dim3(32, B_SZ), 256, 0, stream>>>(hidden, w1, b1, w2, b2, logits);
    boundary_scan_kernel<<<B_SZ, 256, 0, stream>>>(logits, amask, segst, segid, nb, tp, smask);
    pool_accum_kernel<<<dim3(128, B_SZ), 256, 0, stream>>>(hidden, segid, pooled);
    pool_final_kernel<<<dim3(NSEG, B_SZ), 256, 0, stream>>>(pooled, segst);
}